// Round 6
// baseline (227.533 us; speedup 1.0000x reference)
//
#include <hip/hip_runtime.h>

// out[i] = cos(x[i]) * cos(theta[i & 63])
// B,S,E = 8,4096,1024; HD = 64. Pure elementwise streaming, memory-bound.
// Kernel roofline: 268 MB @ ~6.3 TB/s ~= 43 us.
//
// Round-6 probe: explicit load-batching. Previous version interleaved
// load/cos/store per unroll window; if the compiler kept only 1-2 loads in
// flight per wave, store back-pressure serializes HBM traffic. Here each
// batch issues 4 independent nontemporal 16B loads into registers BEFORE any
// compute/store, guaranteeing 4 global_load_dwordx4 outstanding per wave.
// - f32x4 ext_vector (HIP float4 class is rejected by nontemporal builtins).
// - theta phase (tid*4)&63 is grid-stride-invariant -> 4 cos hoisted.
// - 2048 blocks x 256 = 32 waves/CU (max occupancy), 16 exact iterations.

typedef float f32x4 __attribute__((ext_vector_type(4)));

__global__ __launch_bounds__(256) void qattn_kernel(
    const float* __restrict__ x,
    const float* __restrict__ theta,
    float* __restrict__ out,
    int n4)  // number of float4 elements
{
    const int tid    = blockIdx.x * blockDim.x + threadIdx.x;
    const int stride = gridDim.x * blockDim.x;  // multiple of 16 float4s

    const int base = (tid * 4) & 63;
    const float c0 = __cosf(theta[base + 0]);
    const float c1 = __cosf(theta[base + 1]);
    const float c2 = __cosf(theta[base + 2]);
    const float c3 = __cosf(theta[base + 3]);

    const f32x4* __restrict__ x4   = reinterpret_cast<const f32x4*>(x);
    f32x4* __restrict__       out4 = reinterpret_cast<f32x4*>(out);

    const int iters   = n4 / stride;      // == 16 at bench shape
    const int batches = iters / 4;        // == 4

    for (int b = 0; b < batches; ++b) {
        f32x4 v[4];
        // Phase 1: issue all 4 loads (independent, no consumer between them)
#pragma unroll
        for (int j = 0; j < 4; ++j) {
            v[j] = __builtin_nontemporal_load(&x4[tid + (b * 4 + j) * stride]);
        }
        // Phase 2: compute + store
#pragma unroll
        for (int j = 0; j < 4; ++j) {
            f32x4 r;
            r.x = __cosf(v[j].x) * c0;
            r.y = __cosf(v[j].y) * c1;
            r.z = __cosf(v[j].z) * c2;
            r.w = __cosf(v[j].w) * c3;
            __builtin_nontemporal_store(r, &out4[tid + (b * 4 + j) * stride]);
        }
    }

    // tails (empty at the bench shape)
    for (int i = tid + batches * 4 * stride; i < n4; i += stride) {
        f32x4 v = x4[i];
        f32x4 r;
        r.x = __cosf(v.x) * c0;
        r.y = __cosf(v.y) * c1;
        r.z = __cosf(v.z) * c2;
        r.w = __cosf(v.w) * c3;
        out4[i] = r;
    }
}

extern "C" void kernel_launch(void* const* d_in, const int* in_sizes, int n_in,
                              void* d_out, int out_size, void* d_ws, size_t ws_size,
                              hipStream_t stream) {
    const float* x     = (const float*)d_in[0];  // (B,S,E) f32
    const float* theta = (const float*)d_in[1];  // (64,) f32
    float* out         = (float*)d_out;          // (B,S,E) f32

    const int n  = out_size;  // 33,554,432
    const int n4 = n / 4;     // 8,388,608 float4s

    const int block = 256;
    int grid = (n4 + block - 1) / block;
    if (grid > 2048) grid = 2048;  // 32 waves/CU; stride stays %16==0

    qattn_kernel<<<grid, block, 0, stream>>>(x, theta, out, n4);
}